// Round 15
// baseline (442.372 us; speedup 1.0000x reference)
//
#include <hip/hip_runtime.h>

#define HW 16384   // 128*128

typedef _Float16 half8  __attribute__((ext_vector_type(8)));
typedef _Float16 half4v __attribute__((ext_vector_type(4)));
typedef float    f32x4  __attribute__((ext_vector_type(4)));

typedef __attribute__((address_space(3))) unsigned int lds_u32;
typedef const __attribute__((address_space(1))) unsigned int glb_u32;

// direct global->LDS 16B DMA (no VGPR round trip)
__device__ __forceinline__ void gl_lds16(const void* g, void* l) {
    __builtin_amdgcn_global_load_lds((glb_u32*)g, (lds_u32*)l, 16, 0, 0);
}

// counted vmcnt wait (literal immediates only)
template <int N> __device__ __forceinline__ void wait_vm() {
    static_assert(N == 0 || N == 11 || N == 19, "unsupported vmcnt literal");
    if constexpr (N == 0)  asm volatile("s_waitcnt vmcnt(0)" ::: "memory");
    if constexpr (N == 11) asm volatile("s_waitcnt vmcnt(11)" ::: "memory");
    if constexpr (N == 19) asm volatile("s_waitcnt vmcnt(19)" ::: "memory");
}

// ---------------- zero fill (float4 granularity) ----------------
__global__ void zero4(float4* __restrict__ p, int n4) {
    int i = blockIdx.x * 256 + threadIdx.x;
    if (i < n4) p[i] = make_float4(0.f, 0.f, 0.f, 0.f);
}

__global__ void write_code_f32(float* out, float v) {
    if (threadIdx.x == 0 && blockIdx.x == 0) out[0] = v;
}

// ---------------- border-only zero: cells with y in {0,129} or x in {0,129} ----------------
__global__ void border_zero(_Float16* __restrict__ base, int D, int CS) {
    int idx = blockIdx.x * 256 + threadIdx.x;
    int gpc = CS / 8;
    int total = D * 516 * gpc;
    if (idx >= total) return;
    int g = idx % gpc;
    int c = (idx / gpc) % 516;
    int d = idx / (gpc * 516);
    int y, x;
    if (c < 130)      { y = 0;           x = c; }
    else if (c < 260) { y = 129;         x = c - 130; }
    else if (c < 388) { y = c - 260 + 1; x = 0; }
    else              { y = c - 388 + 1; x = 129; }
    *(float4*)(base + ((size_t)(d * 130 + y) * 130 + x) * CS + g * 8) =
        make_float4(0.f, 0.f, 0.f, 0.f);
}

// ---------------- fused weight pack: all 11 layers in one dispatch ----------------
struct PackDesc {
    const float* src[11];
    int dstoff[11];
    int cum[12];
    int cinr[11];
    int cinp[11];
    int cout[11];
    int khw[11];
};

__global__ void pack_all(PackDesc pd, _Float16* __restrict__ AP) {
    int u = blockIdx.x * 256 + threadIdx.x;
    if (u >= pd.cum[11]) return;
    int s = 0;
    while (u >= pd.cum[s + 1]) ++s;
    int idx = u - pd.cum[s];
    const int CINr = pd.cinr[s], CINp = pd.cinp[s], KHW = pd.khw[s];
    const int KD = 3;
    const int NSTEPS = KD * KHW * KHW * (CINp / 32);
    const float* W = pd.src[s];
    int lane = idx & 63;
    int st   = (idx >> 6) % NSTEPS;
    int grp  = idx / (NSTEPS * 64);
    int k0  = st * 32 + (lane >> 4) * 8;
    int t   = k0 / CINp;
    int ci0 = k0 % CINp;
    int co  = grp * 16 + (lane & 15);
    int khw2 = KHW * KHW;
    int dz = t / khw2, r = t % khw2, dy = r / KHW, dx = r % KHW;
    half8 hv;
    for (int j = 0; j < 8; ++j) {
        int ci = ci0 + j;
        float wv = (ci < CINr)
            ? W[(((size_t)co * CINr + ci) * KD + dz) * khw2 + dy * KHW + dx] : 0.0f;
        hv[j] = (_Float16)wv;
    }
    *(half8*)(AP + pd.dstoff[s] + ((size_t)(grp * NSTEPS + st) * 64 + lane) * 8) = hv;
}

// ---------------- scatter voxels into [z][130][130][40] f16 grid ----------------
__global__ void scatter_f16(const float* __restrict__ vf, const int* __restrict__ coors,
                            _Float16* __restrict__ act, unsigned char* __restrict__ occ, int n) {
    int i = blockIdx.x * 256 + threadIdx.x;
    if (i >= n) return;
    int z = coors[i * 4 + 1];
    int y = coors[i * 4 + 2];
    int x = coors[i * 4 + 3];
    size_t cell = ((size_t)(z * 130 + (y + 1)) * 130 + (x + 1)) * 40;
    for (int c = 0; c < 16; ++c) act[cell + c] = (_Float16)vf[i * 16 + c];
    occ[z * HW + y * 128 + x] = 1;
}

// ---------------- pool occupancy (u8) over z: D16 -> D8 -> D4 -> D2 ----------------
__global__ void pool_occ(const unsigned char* __restrict__ o0, unsigned char* __restrict__ o1,
                         unsigned char* __restrict__ o2, unsigned char* __restrict__ o3) {
    int p = blockIdx.x * 256 + threadIdx.x;
    if (p >= HW) return;
    unsigned char a[16];
    for (int z = 0; z < 16; ++z) a[z] = o0[z * HW + p];
    for (int z = 0; z < 8; ++z) { a[z] = a[2 * z] | a[2 * z + 1]; o1[z * HW + p] = a[z]; }
    for (int z = 0; z < 4; ++z) { a[z] = a[2 * z] | a[2 * z + 1]; o2[z * HW + p] = a[z]; }
    for (int z = 0; z < 2; ++z) { a[z] = a[2 * z] | a[2 * z + 1]; o3[z * HW + p] = a[z]; }
}

// ---------------- MFMA implicit-GEMM conv, LDS double-buffered (T3/T4-lite) ----------------
// act : [DIN][130][130][CS=CINp+8] f16 (y/x padded by 1; border real-channels zero).
// Pipeline per block: stage(buf0,dz0); loop { [bar] stage(buf^1,dz+1);
//   vmcnt(G) [counted, never 0 mid-loop]; bar; compute(buf) }.
// Stage = uniform G gl_lds16 per thread (granules padded to 256-multiple; slack
// reads stay in-ws, land in LDS slots compute never reads).
// out : intermediate [DOUT][130][130][COUT+8] f16 ; FINAL [COUT*2][128][128] f32
// block: 4 waves = 2 output rows x 128 x, each wave = ALL COUT x 64 px. 1 block/CU.
template <int CINp, int COUT, int KD, int KHW, int SZ, int DIN, int DOUT, bool FINAL>
__global__ __launch_bounds__(256, 1)
void conv_mfma(const _Float16* __restrict__ act, const _Float16* __restrict__ apack,
               const float* __restrict__ gm, const float* __restrict__ bt,
               const float* __restrict__ mn, const float* __restrict__ vr,
               const unsigned char* __restrict__ occ, void* __restrict__ outv) {
    constexpr int PADXY  = KHW / 2;
    constexpr int CB     = CINp / 32;
    constexpr int MG     = COUT / 16;
    constexpr int NSTEPS = KD * KHW * KHW * CB;
    constexpr int CS     = CINp + 8;
    constexpr int OCS    = COUT + 8;
    constexpr int NGRAN  = 4 * 130 * CS / 8;     // real granules per stripe
    constexpr int G      = (NGRAN + 255) / 256;  // uniform loads per thread
    constexpr int GP     = G * 256;              // padded granules
    constexpr int OFS    = 1 - PADXY;
    constexpr int NWG    = DOUT * 64;

    __shared__ _Float16 smem[2][GP * 8];

    const int bid0 = blockIdx.x;
    const int bid = (bid0 & 7) * (NWG / 8) + (bid0 >> 3);   // XCD-chunked swizzle
    const int yp = bid & 63;
    const int z0 = bid >> 6;
    const int y0 = yp * 2;
    const int tid  = threadIdx.x;
    const int w    = tid >> 6;
    const int lane = tid & 63;
    const int ylocal = w >> 1;
    const int x0w    = (w & 1) * 64;
    const int n  = lane & 15;
    const int kg = lane >> 4;

    f32x4 acc[MG][4];
    #pragma unroll
    for (int m = 0; m < MG; ++m)
        #pragma unroll
        for (int t = 0; t < 4; ++t) { acc[m][t][0] = 0.f; acc[m][t][1] = 0.f; acc[m][t][2] = 0.f; acc[m][t][3] = 0.f; }

    const int zb = z0 * SZ;
    const int dzlo = (zb == 0) ? 1 : 0;
    const int dzhi = (zb + KD - 1 > DIN) ? (KD - 1) : KD;

    auto stage = [&](int bufi, int dz) {
        const int zi = zb + dz - 1;
        const _Float16* src = act + (size_t)(zi * 130 + y0) * (130 * CS);
        _Float16* dst = &smem[bufi][0];
        #pragma unroll
        for (int it = 0; it < G; ++it) {
            const size_t g = (size_t)it * 256 + tid;
            gl_lds16(src + g * 8, dst + g * 8);
        }
    };

    stage(0, dzlo);
    int cur = 0;
    for (int dz = dzlo; dz < dzhi; ++dz) {
        const bool has_next = (dz + 1 < dzhi);
        if (dz > dzlo) __syncthreads();           // prev compute done before overwrite
        if (has_next) stage(cur ^ 1, dz + 1);     // issue next stripe (hides under compute)
        if (has_next) wait_vm<G>(); else wait_vm<0>();   // current stripe's loads done
        __syncthreads();
        const _Float16* sm = &smem[cur][0];
        #pragma unroll
        for (int dy = 0; dy < KHW; ++dy) {
            #pragma unroll
            for (int dx = 0; dx < KHW; ++dx) {
                #pragma unroll
                for (int cb = 0; cb < CB; ++cb) {
                    const int sabs = dz * (KHW * KHW * CB) + (dy * KHW + dx) * CB + cb;
                    half8 a[MG];
                    #pragma unroll
                    for (int mg = 0; mg < MG; ++mg)
                        a[mg] = *(const half8*)(apack + ((size_t)(mg * NSTEPS + sabs) * 64 + lane) * 8);
                    const _Float16* bp = sm
                        + ((ylocal + dy + OFS) * 130 + x0w + n + dx + OFS) * CS + cb * 32 + kg * 8;
                    #pragma unroll
                    for (int nt = 0; nt < 4; ++nt) {
                        half8 b = *(const half8*)(bp + nt * 16 * CS);
                        #pragma unroll
                        for (int mg = 0; mg < MG; ++mg)
                            acc[mg][nt] = __builtin_amdgcn_mfma_f32_16x16x32_f16(a[mg], b, acc[mg][nt], 0, 0, 0);
                    }
                }
            }
        }
        cur ^= 1;
    }

    // ---- epilogue: BN + ReLU + occ, store ----
    const int yo = y0 + ylocal;
    #pragma unroll
    for (int mg = 0; mg < MG; ++mg) {
        const int co0 = mg * 16 + kg * 4;
        const f32x4 gv = *(const f32x4*)(gm + co0);
        const f32x4 bv = *(const f32x4*)(bt + co0);
        const f32x4 mv = *(const f32x4*)(mn + co0);
        const f32x4 vv = *(const f32x4*)(vr + co0);
        float sc[4], sh[4];
        #pragma unroll
        for (int r = 0; r < 4; ++r) {
            sc[r] = gv[r] * __frsqrt_rn(vv[r] + 1e-5f);
            sh[r] = bv[r] - mv[r] * sc[r];
        }
        #pragma unroll
        for (int nt = 0; nt < 4; ++nt) {
            const int x = x0w + nt * 16 + n;
            const float occv = (float)occ[z0 * HW + yo * 128 + x];
            float v0 = fmaxf(fmaf(acc[mg][nt][0], sc[0], sh[0]), 0.f) * occv;
            float v1 = fmaxf(fmaf(acc[mg][nt][1], sc[1], sh[1]), 0.f) * occv;
            float v2 = fmaxf(fmaf(acc[mg][nt][2], sc[2], sh[2]), 0.f) * occv;
            float v3 = fmaxf(fmaf(acc[mg][nt][3], sc[3], sh[3]), 0.f) * occv;
            if constexpr (FINAL) {
                float* o = (float*)outv;
                const int sp = yo * 128 + x;
                o[((size_t)(co0 + 0) * 2 + z0) * HW + sp] = v0;
                o[((size_t)(co0 + 1) * 2 + z0) * HW + sp] = v1;
                o[((size_t)(co0 + 2) * 2 + z0) * HW + sp] = v2;
                o[((size_t)(co0 + 3) * 2 + z0) * HW + sp] = v3;
            } else {
                _Float16* o = (_Float16*)outv;
                half4v hv;
                hv[0] = (_Float16)v0; hv[1] = (_Float16)v1;
                hv[2] = (_Float16)v2; hv[3] = (_Float16)v3;
                *(half4v*)(o + ((size_t)(z0 * 130 + (yo + 1)) * 130 + (x + 1)) * OCS + co0) = hv;
            }
        }
    }
}

extern "C" void kernel_launch(void* const* d_in, const int* in_sizes, int n_in,
                              void* d_out, int out_size, void* d_ws, size_t ws_size,
                              hipStream_t stream) {
    const float* vf    = (const float*)d_in[0];
    const int*   coors = (const int*)d_in[1];
    const float* w0    = (const float*)d_in[2];
    const float* w1    = (const float*)d_in[3];
    const float* w2    = (const float*)d_in[4];
    const float* w64   = (const float*)d_in[5];
    const float* w10   = (const float*)d_in[6];
    const float* g32   = (const float*)d_in[7];
    const float* b32   = (const float*)d_in[8];
    const float* m32   = (const float*)d_in[9];
    const float* v32   = (const float*)d_in[10];
    const float* g64   = (const float*)d_in[11];
    const float* b64   = (const float*)d_in[12];
    const float* m64   = (const float*)d_in[13];
    const float* v64   = (const float*)d_in[14];
    const int N = in_sizes[0] / 16;

    float* out_f = (float*)d_out;

    // ---- workspace layout (bytes) ----
    const size_t R0 = 0;
    const size_t R1 = 21632000;
    const size_t R3 = 43264000;
    const size_t OFF_OCC0 = 62732800;
    const size_t OFF_OCC1 = 62994944;
    const size_t OFF_OCC2 = 63126016;
    const size_t OFF_OCC3 = 63191552;
    const size_t OFF_AP   = 63224320;
    const size_t TOTAL_BYTES = 65018368;

    if (ws_size < TOTAL_BYTES) {
        write_code_f32<<<dim3(1), dim3(64), 0, stream>>>(out_f, 1.0e8f);
        return;
    }

    char* wsb = (char*)d_ws;
    _Float16* A0p = (_Float16*)(wsb + R0);
    _Float16* A1p = (_Float16*)(wsb + R1);
    _Float16* A3p = (_Float16*)(wsb + R3);
    _Float16* A2p = A1p;
    unsigned char* occ0 = (unsigned char*)(wsb + OFF_OCC0);
    unsigned char* occ1 = (unsigned char*)(wsb + OFF_OCC1);
    unsigned char* occ2 = (unsigned char*)(wsb + OFF_OCC2);
    unsigned char* occ3 = (unsigned char*)(wsb + OFF_OCC3);
    _Float16* AP = (_Float16*)(wsb + OFF_AP);

    const size_t W_A0 = 0, W_A1 = 27648, W_A2 = 55296, W_A3 = 110592, W_A10 = 884736;

    // ---- prologue zeroing: R0 full (scatter target) + occ0, borders elsewhere ----
    zero4<<<dim3((21632000 / 16 + 255) / 256), dim3(256), 0, stream>>>((float4*)(wsb + R0), 21632000 / 16);
    zero4<<<dim3((262144 / 16 + 255) / 256), dim3(256), 0, stream>>>((float4*)occ0, 262144 / 16);
    {
        int t1 = 16 * 516 * (40 / 8);
        border_zero<<<dim3((t1 + 255) / 256), dim3(256), 0, stream>>>(A1p, 16, 40);
        int t3 = 8 * 516 * (72 / 8);
        border_zero<<<dim3((t3 + 255) / 256), dim3(256), 0, stream>>>(A3p, 8, 72);
    }

    // ---- fused weight pack ----
    {
        PackDesc pd;
        int units[11] = {3456, 3456, 6912, 13824, 13824, 13824, 13824, 13824, 13824, 13824, 1536};
        const float* srcs[11] = {w0, w1, w2,
                                 w64 + 0 * 110592, w64 + 1 * 110592, w64 + 2 * 110592,
                                 w64 + 3 * 110592, w64 + 4 * 110592, w64 + 5 * 110592,
                                 w64 + 6 * 110592, w10};
        int offs[11] = {(int)W_A0, (int)W_A1, (int)W_A2,
                        (int)(W_A3 + 0 * 110592), (int)(W_A3 + 1 * 110592), (int)(W_A3 + 2 * 110592),
                        (int)(W_A3 + 3 * 110592), (int)(W_A3 + 4 * 110592), (int)(W_A3 + 5 * 110592),
                        (int)(W_A3 + 6 * 110592), (int)W_A10};
        int cinr[11] = {16, 32, 32, 64, 64, 64, 64, 64, 64, 64, 64};
        int cinp[11] = {32, 32, 32, 64, 64, 64, 64, 64, 64, 64, 64};
        int cout[11] = {32, 32, 64, 64, 64, 64, 64, 64, 64, 64, 64};
        int khw[11]  = {3, 3, 3, 3, 3, 3, 3, 3, 3, 3, 1};
        int c = 0;
        for (int i = 0; i < 11; ++i) {
            pd.src[i] = srcs[i]; pd.dstoff[i] = offs[i]; pd.cum[i] = c; c += units[i];
            pd.cinr[i] = cinr[i]; pd.cinp[i] = cinp[i]; pd.cout[i] = cout[i]; pd.khw[i] = khw[i];
        }
        pd.cum[11] = c;
        pack_all<<<dim3((c + 255) / 256), dim3(256), 0, stream>>>(pd, AP);
    }

    scatter_f16<<<dim3((N + 255) / 256), dim3(256), 0, stream>>>(vf, coors, A0p, occ0, N);
    pool_occ<<<dim3(HW / 256), dim3(256), 0, stream>>>(occ0, occ1, occ2, occ3);

    // L0: 16(pad32)->32, D16  (R0 -> R1)
    conv_mfma<32, 32, 3, 3, 1, 16, 16, false><<<dim3(16 * 64), dim3(256), 0, stream>>>(
        A0p, AP + W_A0, g32, b32, m32, v32, occ0, A1p);
    // L1: 32->32, D16  (R1 -> R0)
    conv_mfma<32, 32, 3, 3, 1, 16, 16, false><<<dim3(16 * 64), dim3(256), 0, stream>>>(
        A1p, AP + W_A1, g32 + 32, b32 + 32, m32 + 32, v32 + 32, occ0, A0p);
    // R1's P32 data dead -> zero R2's borders (D8/CS72)
    {
        int t = 8 * 516 * (72 / 8);
        border_zero<<<dim3((t + 255) / 256), dim3(256), 0, stream>>>(A2p, 8, 72);
    }
    // L2: 32->64, stride-z 2, D16->8  (R0 -> R2)
    conv_mfma<32, 64, 3, 3, 2, 16, 8, false><<<dim3(8 * 64), dim3(256), 0, stream>>>(
        A0p, AP + W_A2, g64, b64, m64, v64, occ1, A2p);
    // R0 dead -> zero D4A borders
    {
        int t = 4 * 516 * (72 / 8);
        border_zero<<<dim3((t + 255) / 256), dim3(256), 0, stream>>>(A0p, 4, 72);
    }
    // L3..L5: 64->64, D8  (R2 -> R3 -> R2 -> R3)
    conv_mfma<64, 64, 3, 3, 1, 8, 8, false><<<dim3(8 * 64), dim3(256), 0, stream>>>(
        A2p, AP + W_A3 + 0 * 110592, g64 + 64, b64 + 64, m64 + 64, v64 + 64, occ1, A3p);
    conv_mfma<64, 64, 3, 3, 1, 8, 8, false><<<dim3(8 * 64), dim3(256), 0, stream>>>(
        A3p, AP + W_A3 + 1 * 110592, g64 + 128, b64 + 128, m64 + 128, v64 + 128, occ1, A2p);
    conv_mfma<64, 64, 3, 3, 1, 8, 8, false><<<dim3(8 * 64), dim3(256), 0, stream>>>(
        A2p, AP + W_A3 + 2 * 110592, g64 + 192, b64 + 192, m64 + 192, v64 + 192, occ1, A3p);
    // L6: 64->64, stride-z 2, D8->4  (R3 -> D4A)
    conv_mfma<64, 64, 3, 3, 2, 8, 4, false><<<dim3(4 * 64), dim3(256), 0, stream>>>(
        A3p, AP + W_A3 + 3 * 110592, g64 + 256, b64 + 256, m64 + 256, v64 + 256, occ2, A0p);
    // R2 dead -> zero D4B borders
    {
        int t = 4 * 516 * (72 / 8);
        border_zero<<<dim3((t + 255) / 256), dim3(256), 0, stream>>>(A1p, 4, 72);
    }
    // L7..L9: 64->64, D4  (D4A -> D4B -> D4A -> D4B)
    conv_mfma<64, 64, 3, 3, 1, 4, 4, false><<<dim3(4 * 64), dim3(256), 0, stream>>>(
        A0p, AP + W_A3 + 4 * 110592, g64 + 320, b64 + 320, m64 + 320, v64 + 320, occ2, A1p);
    conv_mfma<64, 64, 3, 3, 1, 4, 4, false><<<dim3(4 * 64), dim3(256), 0, stream>>>(
        A1p, AP + W_A3 + 5 * 110592, g64 + 384, b64 + 384, m64 + 384, v64 + 384, occ2, A0p);
    conv_mfma<64, 64, 3, 3, 1, 4, 4, false><<<dim3(4 * 64), dim3(256), 0, stream>>>(
        A0p, AP + W_A3 + 6 * 110592, g64 + 448, b64 + 448, m64 + 448, v64 + 448, occ2, A1p);
    // L10: 64->64, kernel (3,1,1), stride-z 2, D4->2, f32 out -> d_out  (D4B -> out)
    conv_mfma<64, 64, 3, 1, 2, 4, 2, true><<<dim3(2 * 64), dim3(256), 0, stream>>>(
        A1p, AP + W_A10, g64 + 512, b64 + 512, m64 + 512, v64 + 512, occ3, out_f);
}

// Round 17
// 334.584 us; speedup vs baseline: 1.3222x; 1.3222x over previous
//
#include <hip/hip_runtime.h>

#define HW 16384   // 128*128

typedef _Float16 half8  __attribute__((ext_vector_type(8)));
typedef _Float16 half4v __attribute__((ext_vector_type(4)));
typedef float    f32x4  __attribute__((ext_vector_type(4)));

typedef __attribute__((address_space(3))) unsigned int lds_u32;
typedef const __attribute__((address_space(1))) unsigned int glb_u32;

// direct global->LDS 16B DMA (no VGPR round trip)
__device__ __forceinline__ void gl_lds16(const void* g, void* l) {
    __builtin_amdgcn_global_load_lds((glb_u32*)g, (lds_u32*)l, 16, 0, 0);
}

// ---------------- zero fill (float4 granularity) ----------------
__global__ void zero4(float4* __restrict__ p, int n4) {
    int i = blockIdx.x * 256 + threadIdx.x;
    if (i < n4) p[i] = make_float4(0.f, 0.f, 0.f, 0.f);
}

__global__ void write_code_f32(float* out, float v) {
    if (threadIdx.x == 0 && blockIdx.x == 0) out[0] = v;
}

// ---------------- border-only zero: cells with y in {0,129} or x in {0,129} ----------------
__global__ void border_zero(_Float16* __restrict__ base, int D, int CS) {
    int idx = blockIdx.x * 256 + threadIdx.x;
    int gpc = CS / 8;
    int total = D * 516 * gpc;
    if (idx >= total) return;
    int g = idx % gpc;
    int c = (idx / gpc) % 516;
    int d = idx / (gpc * 516);
    int y, x;
    if (c < 130)      { y = 0;           x = c; }
    else if (c < 260) { y = 129;         x = c - 130; }
    else if (c < 388) { y = c - 260 + 1; x = 0; }
    else              { y = c - 388 + 1; x = 129; }
    *(float4*)(base + ((size_t)(d * 130 + y) * 130 + x) * CS + g * 8) =
        make_float4(0.f, 0.f, 0.f, 0.f);
}

// ---------------- fused weight pack: all 11 layers in one dispatch ----------------
struct PackDesc {
    const float* src[11];
    int dstoff[11];
    int cum[12];
    int cinr[11];
    int cinp[11];
    int cout[11];
    int khw[11];
};

__global__ void pack_all(PackDesc pd, _Float16* __restrict__ AP) {
    int u = blockIdx.x * 256 + threadIdx.x;
    if (u >= pd.cum[11]) return;
    int s = 0;
    while (u >= pd.cum[s + 1]) ++s;
    int idx = u - pd.cum[s];
    const int CINr = pd.cinr[s], CINp = pd.cinp[s], KHW = pd.khw[s];
    const int KD = 3;
    const int NSTEPS = KD * KHW * KHW * (CINp / 32);
    const float* W = pd.src[s];
    int lane = idx & 63;
    int st   = (idx >> 6) % NSTEPS;
    int grp  = idx / (NSTEPS * 64);
    int k0  = st * 32 + (lane >> 4) * 8;
    int t   = k0 / CINp;
    int ci0 = k0 % CINp;
    int co  = grp * 16 + (lane & 15);
    int khw2 = KHW * KHW;
    int dz = t / khw2, r = t % khw2, dy = r / KHW, dx = r % KHW;
    half8 hv;
    for (int j = 0; j < 8; ++j) {
        int ci = ci0 + j;
        float wv = (ci < CINr)
            ? W[(((size_t)co * CINr + ci) * KD + dz) * khw2 + dy * KHW + dx] : 0.0f;
        hv[j] = (_Float16)wv;
    }
    *(half8*)(AP + pd.dstoff[s] + ((size_t)(grp * NSTEPS + st) * 64 + lane) * 8) = hv;
}

// ---------------- scatter voxels into [z][130][130][40] f16 grid ----------------
__global__ void scatter_f16(const float* __restrict__ vf, const int* __restrict__ coors,
                            _Float16* __restrict__ act, unsigned char* __restrict__ occ, int n) {
    int i = blockIdx.x * 256 + threadIdx.x;
    if (i >= n) return;
    int z = coors[i * 4 + 1];
    int y = coors[i * 4 + 2];
    int x = coors[i * 4 + 3];
    size_t cell = ((size_t)(z * 130 + (y + 1)) * 130 + (x + 1)) * 40;
    for (int c = 0; c < 16; ++c) act[cell + c] = (_Float16)vf[i * 16 + c];
    occ[z * HW + y * 128 + x] = 1;
}

// ---------------- pool occupancy (u8) over z: D16 -> D8 -> D4 -> D2 ----------------
__global__ void pool_occ(const unsigned char* __restrict__ o0, unsigned char* __restrict__ o1,
                         unsigned char* __restrict__ o2, unsigned char* __restrict__ o3) {
    int p = blockIdx.x * 256 + threadIdx.x;
    if (p >= HW) return;
    unsigned char a[16];
    for (int z = 0; z < 16; ++z) a[z] = o0[z * HW + p];
    for (int z = 0; z < 8; ++z) { a[z] = a[2 * z] | a[2 * z + 1]; o1[z * HW + p] = a[z]; }
    for (int z = 0; z < 4; ++z) { a[z] = a[2 * z] | a[2 * z + 1]; o2[z * HW + p] = a[z]; }
    for (int z = 0; z < 2; ++z) { a[z] = a[2 * z] | a[2 * z + 1]; o3[z * HW + p] = a[z]; }
}

// ---------------- MFMA implicit-GEMM conv + BN + ReLU + occ, LDS-staged ----------------
// act : [DIN][130][130][CS=CINp+8] f16 (y/x padded by 1; border real-channels zero).
// Staging: global_load_lds 16B granules (guarded tail), LDS == linear stripe image.
// out : intermediate [DOUT][130][130][COUT+8] f16 ; FINAL [COUT*2][128][128] f32
// block: 512 thr = 8 waves = (ylocal, x-half, co-half); each wave = COUT/2 x 64 px.
// 74.9 KB LDS -> 2 blocks/CU = 16 waves/CU = 4 waves/SIMD (D16/D8); serial stage.
template <int CINp, int COUT, int KD, int KHW, int SZ, int DIN, int DOUT, bool FINAL>
__global__ __launch_bounds__(512, 4)
void conv_mfma(const _Float16* __restrict__ act, const _Float16* __restrict__ apack,
               const float* __restrict__ gm, const float* __restrict__ bt,
               const float* __restrict__ mn, const float* __restrict__ vr,
               const unsigned char* __restrict__ occ, void* __restrict__ outv) {
    constexpr int PADXY  = KHW / 2;
    constexpr int CB     = CINp / 32;
    constexpr int MGT    = COUT / 16;            // total co-groups
    constexpr int MGW    = (MGT + 1) / 2;        // co-groups per wave (half)
    constexpr int NSTEPS = KD * KHW * KHW * CB;
    constexpr int CS     = CINp + 8;
    constexpr int OCS    = COUT + 8;
    constexpr int NGRAN  = 4 * 130 * CS / 8;
    constexpr int NIT    = (NGRAN + 511) / 512;
    constexpr int OFS    = 1 - PADXY;
    constexpr int NWG    = DOUT * 64;

    __shared__ _Float16 smem[4 * 130 * CS];

    const int bid0 = blockIdx.x;
    const int bid = (bid0 & 7) * (NWG / 8) + (bid0 >> 3);   // XCD-chunked swizzle
    const int yp = bid & 63;
    const int z0 = bid >> 6;
    const int y0 = yp * 2;
    const int tid  = threadIdx.x;
    const int w    = tid >> 6;
    const int lane = tid & 63;
    const int ylocal = w >> 2;            // 0..1
    const int x0w    = ((w >> 1) & 1) * 64;
    const int chh    = (MGT > 1) ? (w & 1) : 0;   // co-half
    const int n  = lane & 15;
    const int kg = lane >> 4;

    f32x4 acc[MGW][4];
    #pragma unroll
    for (int m = 0; m < MGW; ++m)
        #pragma unroll
        for (int t = 0; t < 4; ++t) { acc[m][t][0] = 0.f; acc[m][t][1] = 0.f; acc[m][t][2] = 0.f; acc[m][t][3] = 0.f; }

    const int zb = z0 * SZ;
    const int dzlo = (zb == 0) ? 1 : 0;
    const int dzhi = (zb + KD - 1 > DIN) ? (KD - 1) : KD;

    for (int dz = dzlo; dz < dzhi; ++dz) {
        const int zi = zb + dz - 1;
        __syncthreads();   // previous iteration's LDS reads complete
        // ---- stage 4-row stripe via global_load_lds ----
        const _Float16* src = act + (size_t)(zi * 130 + y0) * (130 * CS);
        #pragma unroll
        for (int it = 0; it < NIT; ++it) {
            int g = it * 512 + tid;
            if (g < NGRAN) gl_lds16(src + (size_t)g * 8, smem + (size_t)g * 8);
        }
        asm volatile("s_waitcnt vmcnt(0)" ::: "memory");
        __syncthreads();
        // ---- K-loop over taps (straight-line) ----
        #pragma unroll
        for (int dy = 0; dy < KHW; ++dy) {
            #pragma unroll
            for (int dx = 0; dx < KHW; ++dx) {
                #pragma unroll
                for (int cb = 0; cb < CB; ++cb) {
                    const int sabs = dz * (KHW * KHW * CB) + (dy * KHW + dx) * CB + cb;
                    half8 a[MGW];
                    #pragma unroll
                    for (int mg = 0; mg < MGW; ++mg)
                        a[mg] = *(const half8*)(apack
                            + ((size_t)((chh * MGW + mg) * NSTEPS + sabs) * 64 + lane) * 8);
                    const _Float16* bp = smem
                        + ((ylocal + dy + OFS) * 130 + x0w + n + dx + OFS) * CS + cb * 32 + kg * 8;
                    #pragma unroll
                    for (int nt = 0; nt < 4; ++nt) {
                        half8 b = *(const half8*)(bp + nt * 16 * CS);
                        #pragma unroll
                        for (int mg = 0; mg < MGW; ++mg)
                            acc[mg][nt] = __builtin_amdgcn_mfma_f32_16x16x32_f16(a[mg], b, acc[mg][nt], 0, 0, 0);
                    }
                }
            }
        }
    }

    // ---- epilogue: BN + ReLU + occ, store ----
    const int yo = y0 + ylocal;
    #pragma unroll
    for (int mg = 0; mg < MGW; ++mg) {
        const int co0 = (chh * MGW + mg) * 16 + kg * 4;
        const f32x4 gv = *(const f32x4*)(gm + co0);
        const f32x4 bv = *(const f32x4*)(bt + co0);
        const f32x4 mv = *(const f32x4*)(mn + co0);
        const f32x4 vv = *(const f32x4*)(vr + co0);
        float sc[4], sh[4];
        #pragma unroll
        for (int r = 0; r < 4; ++r) {
            sc[r] = gv[r] * __frsqrt_rn(vv[r] + 1e-5f);
            sh[r] = bv[r] - mv[r] * sc[r];
        }
        #pragma unroll
        for (int nt = 0; nt < 4; ++nt) {
            const int x = x0w + nt * 16 + n;
            const float occv = (float)occ[z0 * HW + yo * 128 + x];
            float v0 = fmaxf(fmaf(acc[mg][nt][0], sc[0], sh[0]), 0.f) * occv;
            float v1 = fmaxf(fmaf(acc[mg][nt][1], sc[1], sh[1]), 0.f) * occv;
            float v2 = fmaxf(fmaf(acc[mg][nt][2], sc[2], sh[2]), 0.f) * occv;
            float v3 = fmaxf(fmaf(acc[mg][nt][3], sc[3], sh[3]), 0.f) * occv;
            if constexpr (FINAL) {
                float* o = (float*)outv;
                const int sp = yo * 128 + x;
                o[((size_t)(co0 + 0) * 2 + z0) * HW + sp] = v0;
                o[((size_t)(co0 + 1) * 2 + z0) * HW + sp] = v1;
                o[((size_t)(co0 + 2) * 2 + z0) * HW + sp] = v2;
                o[((size_t)(co0 + 3) * 2 + z0) * HW + sp] = v3;
            } else {
                _Float16* o = (_Float16*)outv;
                half4v hv;
                hv[0] = (_Float16)v0; hv[1] = (_Float16)v1;
                hv[2] = (_Float16)v2; hv[3] = (_Float16)v3;
                *(half4v*)(o + ((size_t)(z0 * 130 + (yo + 1)) * 130 + (x + 1)) * OCS + co0) = hv;
            }
        }
    }
}

extern "C" void kernel_launch(void* const* d_in, const int* in_sizes, int n_in,
                              void* d_out, int out_size, void* d_ws, size_t ws_size,
                              hipStream_t stream) {
    const float* vf    = (const float*)d_in[0];
    const int*   coors = (const int*)d_in[1];
    const float* w0    = (const float*)d_in[2];
    const float* w1    = (const float*)d_in[3];
    const float* w2    = (const float*)d_in[4];
    const float* w64   = (const float*)d_in[5];
    const float* w10   = (const float*)d_in[6];
    const float* g32   = (const float*)d_in[7];
    const float* b32   = (const float*)d_in[8];
    const float* m32   = (const float*)d_in[9];
    const float* v32   = (const float*)d_in[10];
    const float* g64   = (const float*)d_in[11];
    const float* b64   = (const float*)d_in[12];
    const float* m64   = (const float*)d_in[13];
    const float* v64   = (const float*)d_in[14];
    const int N = in_sizes[0] / 16;

    float* out_f = (float*)d_out;

    // ---- workspace layout (bytes) ----
    const size_t R0 = 0;
    const size_t R1 = 21632000;
    const size_t R3 = 43264000;
    const size_t OFF_OCC0 = 62732800;
    const size_t OFF_OCC1 = 62994944;
    const size_t OFF_OCC2 = 63126016;
    const size_t OFF_OCC3 = 63191552;
    const size_t OFF_AP   = 63224320;
    const size_t TOTAL_BYTES = 65018368;

    if (ws_size < TOTAL_BYTES) {
        write_code_f32<<<dim3(1), dim3(64), 0, stream>>>(out_f, 1.0e8f);
        return;
    }

    char* wsb = (char*)d_ws;
    _Float16* A0p = (_Float16*)(wsb + R0);
    _Float16* A1p = (_Float16*)(wsb + R1);
    _Float16* A3p = (_Float16*)(wsb + R3);
    _Float16* A2p = A1p;
    unsigned char* occ0 = (unsigned char*)(wsb + OFF_OCC0);
    unsigned char* occ1 = (unsigned char*)(wsb + OFF_OCC1);
    unsigned char* occ2 = (unsigned char*)(wsb + OFF_OCC2);
    unsigned char* occ3 = (unsigned char*)(wsb + OFF_OCC3);
    _Float16* AP = (_Float16*)(wsb + OFF_AP);

    const size_t W_A0 = 0, W_A1 = 27648, W_A2 = 55296, W_A3 = 110592, W_A10 = 884736;

    // ---- prologue zeroing: R0 full (scatter target) + occ0, borders elsewhere ----
    zero4<<<dim3((21632000 / 16 + 255) / 256), dim3(256), 0, stream>>>((float4*)(wsb + R0), 21632000 / 16);
    zero4<<<dim3((262144 / 16 + 255) / 256), dim3(256), 0, stream>>>((float4*)occ0, 262144 / 16);
    {
        int t1 = 16 * 516 * (40 / 8);
        border_zero<<<dim3((t1 + 255) / 256), dim3(256), 0, stream>>>(A1p, 16, 40);
        int t3 = 8 * 516 * (72 / 8);
        border_zero<<<dim3((t3 + 255) / 256), dim3(256), 0, stream>>>(A3p, 8, 72);
    }

    // ---- fused weight pack ----
    {
        PackDesc pd;
        int units[11] = {3456, 3456, 6912, 13824, 13824, 13824, 13824, 13824, 13824, 13824, 1536};
        const float* srcs[11] = {w0, w1, w2,
                                 w64 + 0 * 110592, w64 + 1 * 110592, w64 + 2 * 110592,
                                 w64 + 3 * 110592, w64 + 4 * 110592, w64 + 5 * 110592,
                                 w64 + 6 * 110592, w10};
        int offs[11] = {(int)W_A0, (int)W_A1, (int)W_A2,
                        (int)(W_A3 + 0 * 110592), (int)(W_A3 + 1 * 110592), (int)(W_A3 + 2 * 110592),
                        (int)(W_A3 + 3 * 110592), (int)(W_A3 + 4 * 110592), (int)(W_A3 + 5 * 110592),
                        (int)(W_A3 + 6 * 110592), (int)W_A10};
        int cinr[11] = {16, 32, 32, 64, 64, 64, 64, 64, 64, 64, 64};
        int cinp[11] = {32, 32, 32, 64, 64, 64, 64, 64, 64, 64, 64};
        int cout[11] = {32, 32, 64, 64, 64, 64, 64, 64, 64, 64, 64};
        int khw[11]  = {3, 3, 3, 3, 3, 3, 3, 3, 3, 3, 1};
        int c = 0;
        for (int i = 0; i < 11; ++i) {
            pd.src[i] = srcs[i]; pd.dstoff[i] = offs[i]; pd.cum[i] = c; c += units[i];
            pd.cinr[i] = cinr[i]; pd.cinp[i] = cinp[i]; pd.cout[i] = cout[i]; pd.khw[i] = khw[i];
        }
        pd.cum[11] = c;
        pack_all<<<dim3((c + 255) / 256), dim3(256), 0, stream>>>(pd, AP);
    }

    scatter_f16<<<dim3((N + 255) / 256), dim3(256), 0, stream>>>(vf, coors, A0p, occ0, N);
    pool_occ<<<dim3(HW / 256), dim3(256), 0, stream>>>(occ0, occ1, occ2, occ3);

    // L0: 16(pad32)->32, D16  (R0 -> R1)
    conv_mfma<32, 32, 3, 3, 1, 16, 16, false><<<dim3(16 * 64), dim3(512), 0, stream>>>(
        A0p, AP + W_A0, g32, b32, m32, v32, occ0, A1p);
    // L1: 32->32, D16  (R1 -> R0)
    conv_mfma<32, 32, 3, 3, 1, 16, 16, false><<<dim3(16 * 64), dim3(512), 0, stream>>>(
        A1p, AP + W_A1, g32 + 32, b32 + 32, m32 + 32, v32 + 32, occ0, A0p);
    // R1's P32 data dead -> zero R2's borders (D8/CS72)
    {
        int t = 8 * 516 * (72 / 8);
        border_zero<<<dim3((t + 255) / 256), dim3(256), 0, stream>>>(A2p, 8, 72);
    }
    // L2: 32->64, stride-z 2, D16->8  (R0 -> R2)
    conv_mfma<32, 64, 3, 3, 2, 16, 8, false><<<dim3(8 * 64), dim3(512), 0, stream>>>(
        A0p, AP + W_A2, g64, b64, m64, v64, occ1, A2p);
    // R0 dead -> zero D4A borders
    {
        int t = 4 * 516 * (72 / 8);
        border_zero<<<dim3((t + 255) / 256), dim3(256), 0, stream>>>(A0p, 4, 72);
    }
    // L3..L5: 64->64, D8  (R2 -> R3 -> R2 -> R3)
    conv_mfma<64, 64, 3, 3, 1, 8, 8, false><<<dim3(8 * 64), dim3(512), 0, stream>>>(
        A2p, AP + W_A3 + 0 * 110592, g64 + 64, b64 + 64, m64 + 64, v64 + 64, occ1, A3p);
    conv_mfma<64, 64, 3, 3, 1, 8, 8, false><<<dim3(8 * 64), dim3(512), 0, stream>>>(
        A3p, AP + W_A3 + 1 * 110592, g64 + 128, b64 + 128, m64 + 128, v64 + 128, occ1, A2p);
    conv_mfma<64, 64, 3, 3, 1, 8, 8, false><<<dim3(8 * 64), dim3(512), 0, stream>>>(
        A2p, AP + W_A3 + 2 * 110592, g64 + 192, b64 + 192, m64 + 192, v64 + 192, occ1, A3p);
    // L6: 64->64, stride-z 2, D8->4  (R3 -> D4A)
    conv_mfma<64, 64, 3, 3, 2, 8, 4, false><<<dim3(4 * 64), dim3(512), 0, stream>>>(
        A3p, AP + W_A3 + 3 * 110592, g64 + 256, b64 + 256, m64 + 256, v64 + 256, occ2, A0p);
    // R2 dead -> zero D4B borders
    {
        int t = 4 * 516 * (72 / 8);
        border_zero<<<dim3((t + 255) / 256), dim3(256), 0, stream>>>(A1p, 4, 72);
    }
    // L7..L9: 64->64, D4  (D4A -> D4B -> D4A -> D4B)
    conv_mfma<64, 64, 3, 3, 1, 4, 4, false><<<dim3(4 * 64), dim3(512), 0, stream>>>(
        A0p, AP + W_A3 + 4 * 110592, g64 + 320, b64 + 320, m64 + 320, v64 + 320, occ2, A1p);
    conv_mfma<64, 64, 3, 3, 1, 4, 4, false><<<dim3(4 * 64), dim3(512), 0, stream>>>(
        A1p, AP + W_A3 + 5 * 110592, g64 + 384, b64 + 384, m64 + 384, v64 + 384, occ2, A0p);
    conv_mfma<64, 64, 3, 3, 1, 4, 4, false><<<dim3(4 * 64), dim3(512), 0, stream>>>(
        A0p, AP + W_A3 + 6 * 110592, g64 + 448, b64 + 448, m64 + 448, v64 + 448, occ2, A1p);
    // L10: 64->64, kernel (3,1,1), stride-z 2, D4->2, f32 out -> d_out  (D4B -> out)
    conv_mfma<64, 64, 3, 1, 2, 4, 2, true><<<dim3(2 * 64), dim3(512), 0, stream>>>(
        A1p, AP + W_A10, g64 + 512, b64 + 512, m64 + 512, v64 + 512, occ3, out_f);
}

// Round 19
// 299.307 us; speedup vs baseline: 1.4780x; 1.1179x over previous
//
#include <hip/hip_runtime.h>

#define HW 16384   // 128*128

typedef _Float16 half8  __attribute__((ext_vector_type(8)));
typedef _Float16 half4v __attribute__((ext_vector_type(4)));
typedef float    f32x4  __attribute__((ext_vector_type(4)));

typedef __attribute__((address_space(3))) unsigned int lds_u32;
typedef const __attribute__((address_space(1))) unsigned int glb_u32;

// direct global->LDS 16B DMA (no VGPR round trip)
__device__ __forceinline__ void gl_lds16(const void* g, void* l) {
    __builtin_amdgcn_global_load_lds((glb_u32*)g, (lds_u32*)l, 16, 0, 0);
}

// ---------------- zero fill (float4 granularity) ----------------
__global__ void zero4(float4* __restrict__ p, int n4) {
    int i = blockIdx.x * 256 + threadIdx.x;
    if (i < n4) p[i] = make_float4(0.f, 0.f, 0.f, 0.f);
}

__global__ void write_code_f32(float* out, float v) {
    if (threadIdx.x == 0 && blockIdx.x == 0) out[0] = v;
}

// ---------------- fused weight pack: all 11 layers in one dispatch ----------------
struct PackDesc {
    const float* src[11];
    int dstoff[11];
    int cum[12];
    int cinr[11];
    int cinp[11];
    int cout[11];
    int khw[11];
};

__global__ void pack_all(PackDesc pd, _Float16* __restrict__ AP) {
    int u = blockIdx.x * 256 + threadIdx.x;
    if (u >= pd.cum[11]) return;
    int s = 0;
    while (u >= pd.cum[s + 1]) ++s;
    int idx = u - pd.cum[s];
    const int CINr = pd.cinr[s], CINp = pd.cinp[s], KHW = pd.khw[s];
    const int KD = 3;
    const int NSTEPS = KD * KHW * KHW * (CINp / 32);
    const float* W = pd.src[s];
    int lane = idx & 63;
    int st   = (idx >> 6) % NSTEPS;
    int grp  = idx / (NSTEPS * 64);
    int k0  = st * 32 + (lane >> 4) * 8;
    int t   = k0 / CINp;
    int ci0 = k0 % CINp;
    int co  = grp * 16 + (lane & 15);
    int khw2 = KHW * KHW;
    int dz = t / khw2, r = t % khw2, dy = r / KHW, dx = r % KHW;
    half8 hv;
    for (int j = 0; j < 8; ++j) {
        int ci = ci0 + j;
        float wv = (ci < CINr)
            ? W[(((size_t)co * CINr + ci) * KD + dz) * khw2 + dy * KHW + dx] : 0.0f;
        hv[j] = (_Float16)wv;
    }
    *(half8*)(AP + pd.dstoff[s] + ((size_t)(grp * NSTEPS + st) * 64 + lane) * 8) = hv;
}

// ---------------- scatter voxels into [z][130][130][40] f16 grid ----------------
__global__ void scatter_f16(const float* __restrict__ vf, const int* __restrict__ coors,
                            _Float16* __restrict__ act, unsigned char* __restrict__ occ, int n) {
    int i = blockIdx.x * 256 + threadIdx.x;
    if (i >= n) return;
    int z = coors[i * 4 + 1];
    int y = coors[i * 4 + 2];
    int x = coors[i * 4 + 3];
    size_t cell = ((size_t)(z * 130 + (y + 1)) * 130 + (x + 1)) * 40;
    for (int c = 0; c < 16; ++c) act[cell + c] = (_Float16)vf[i * 16 + c];
    occ[z * HW + y * 128 + x] = 1;
}

// ---------------- pool occupancy (u8) over z: D16 -> D8 -> D4 -> D2 ----------------
__global__ void pool_occ(const unsigned char* __restrict__ o0, unsigned char* __restrict__ o1,
                         unsigned char* __restrict__ o2, unsigned char* __restrict__ o3) {
    int p = blockIdx.x * 256 + threadIdx.x;
    if (p >= HW) return;
    unsigned char a[16];
    for (int z = 0; z < 16; ++z) a[z] = o0[z * HW + p];
    for (int z = 0; z < 8; ++z) { a[z] = a[2 * z] | a[2 * z + 1]; o1[z * HW + p] = a[z]; }
    for (int z = 0; z < 4; ++z) { a[z] = a[2 * z] | a[2 * z + 1]; o2[z * HW + p] = a[z]; }
    for (int z = 0; z < 2; ++z) { a[z] = a[2 * z] | a[2 * z + 1]; o3[z * HW + p] = a[z]; }
}

// ---------------- MFMA implicit-GEMM conv + BN + ReLU + occ, LDS-staged ----------------
// act : [DIN][130][130][CS=CINp+8] f16 (y/x padded by 1; border real-channels zero).
// Staging: global_load_lds 16B granules (guarded tail), LDS == linear stripe image.
// out : intermediate [DOUT][130][130][COUT+8] f16 ; FINAL [COUT*2][128][128] f32.
// Non-FINAL epilogue also ZEROES its output buffer's border cells (writer-covers-
// -output invariant) so no separate border_zero dispatches are needed.
// TR=2: block 512thr = 8 waves (ylocal, x-half, co-half), 2 rows x 128 px, 4-row stripe.
// TR=1: block 512thr = 8 waves (x-half, co-group),        1 row  x 128 px, 3-row stripe
//       (56.2 KB LDS -> 2 blocks/CU on 512-block grids: 4 waves/SIMD on D4 layers).
template <int CINp, int COUT, int KD, int KHW, int SZ, int DIN, int DOUT, bool FINAL, int TR = 2>
__global__ __launch_bounds__(512, 4)
void conv_mfma(const _Float16* __restrict__ act, const _Float16* __restrict__ apack,
               const float* __restrict__ gm, const float* __restrict__ bt,
               const float* __restrict__ mn, const float* __restrict__ vr,
               const unsigned char* __restrict__ occ, void* __restrict__ outv) {
    constexpr int PADXY  = KHW / 2;
    constexpr int CB     = CINp / 32;
    constexpr int MGT    = COUT / 16;                 // total co-groups
    constexpr int MGW    = (TR == 2) ? ((MGT + 1) / 2) : 1;   // co-groups per wave
    static_assert(TR == 2 || MGT == 4, "TR=1 requires COUT=64");
    constexpr int NSTEPS = KD * KHW * KHW * CB;
    constexpr int CS     = CINp + 8;
    constexpr int OCS    = COUT + 8;
    constexpr int SROWS  = TR + 2;                    // staged rows
    constexpr int NGRAN  = SROWS * 130 * CS / 8;
    constexpr int NIT    = (NGRAN + 511) / 512;
    constexpr int OFS    = 1 - PADXY;
    constexpr int NWG    = DOUT * (128 / TR);

    __shared__ _Float16 smem[SROWS * 130 * CS];

    const int bid0 = blockIdx.x;
    const int bid = (bid0 & 7) * (NWG / 8) + (bid0 >> 3);   // XCD-chunked swizzle
    const int yp = (TR == 2) ? (bid & 63) : (bid & 127);
    const int z0 = (TR == 2) ? (bid >> 6) : (bid >> 7);
    const int y0 = yp * TR;
    const int tid  = threadIdx.x;
    const int w    = tid >> 6;
    const int lane = tid & 63;
    const int ylocal = (TR == 2) ? (w >> 2) : 0;
    const int x0w    = (TR == 2) ? (((w >> 1) & 1) * 64) : ((w & 1) * 64);
    const int chsel  = (TR == 2) ? ((MGT > 1) ? (w & 1) : 0) : (w >> 1);
    const int n  = lane & 15;
    const int kg = lane >> 4;

    f32x4 acc[MGW][4];
    #pragma unroll
    for (int m = 0; m < MGW; ++m)
        #pragma unroll
        for (int t = 0; t < 4; ++t) { acc[m][t][0] = 0.f; acc[m][t][1] = 0.f; acc[m][t][2] = 0.f; acc[m][t][3] = 0.f; }

    const int zb = z0 * SZ;
    const int dzlo = (zb == 0) ? 1 : 0;
    const int dzhi = (zb + KD - 1 > DIN) ? (KD - 1) : KD;

    for (int dz = dzlo; dz < dzhi; ++dz) {
        const int zi = zb + dz - 1;
        __syncthreads();   // previous iteration's LDS reads complete
        // ---- stage SROWS-row stripe via global_load_lds ----
        const _Float16* src = act + (size_t)(zi * 130 + y0) * (130 * CS);
        #pragma unroll
        for (int it = 0; it < NIT; ++it) {
            int g = it * 512 + tid;
            if (g < NGRAN) gl_lds16(src + (size_t)g * 8, smem + (size_t)g * 8);
        }
        asm volatile("s_waitcnt vmcnt(0)" ::: "memory");
        __syncthreads();
        // ---- K-loop over taps (straight-line) ----
        #pragma unroll
        for (int dy = 0; dy < KHW; ++dy) {
            #pragma unroll
            for (int dx = 0; dx < KHW; ++dx) {
                #pragma unroll
                for (int cb = 0; cb < CB; ++cb) {
                    const int sabs = dz * (KHW * KHW * CB) + (dy * KHW + dx) * CB + cb;
                    half8 a[MGW];
                    #pragma unroll
                    for (int mg = 0; mg < MGW; ++mg)
                        a[mg] = *(const half8*)(apack
                            + ((size_t)((chsel * MGW + mg) * NSTEPS + sabs) * 64 + lane) * 8);
                    const _Float16* bp = smem
                        + ((ylocal + dy + OFS) * 130 + x0w + n + dx + OFS) * CS + cb * 32 + kg * 8;
                    #pragma unroll
                    for (int nt = 0; nt < 4; ++nt) {
                        half8 b = *(const half8*)(bp + nt * 16 * CS);
                        #pragma unroll
                        for (int mg = 0; mg < MGW; ++mg)
                            acc[mg][nt] = __builtin_amdgcn_mfma_f32_16x16x32_f16(a[mg], b, acc[mg][nt], 0, 0, 0);
                    }
                }
            }
        }
    }

    // ---- epilogue: BN + ReLU + occ, store ----
    const int yo = y0 + ylocal;
    #pragma unroll
    for (int mg = 0; mg < MGW; ++mg) {
        const int co0 = (chsel * MGW + mg) * 16 + kg * 4;
        const f32x4 gv = *(const f32x4*)(gm + co0);
        const f32x4 bv = *(const f32x4*)(bt + co0);
        const f32x4 mv = *(const f32x4*)(mn + co0);
        const f32x4 vv = *(const f32x4*)(vr + co0);
        float sc[4], sh[4];
        #pragma unroll
        for (int r = 0; r < 4; ++r) {
            sc[r] = gv[r] * __frsqrt_rn(vv[r] + 1e-5f);
            sh[r] = bv[r] - mv[r] * sc[r];
        }
        #pragma unroll
        for (int nt = 0; nt < 4; ++nt) {
            const int x = x0w + nt * 16 + n;
            const float occv = (float)occ[z0 * HW + yo * 128 + x];
            float v0 = fmaxf(fmaf(acc[mg][nt][0], sc[0], sh[0]), 0.f) * occv;
            float v1 = fmaxf(fmaf(acc[mg][nt][1], sc[1], sh[1]), 0.f) * occv;
            float v2 = fmaxf(fmaf(acc[mg][nt][2], sc[2], sh[2]), 0.f) * occv;
            float v3 = fmaxf(fmaf(acc[mg][nt][3], sc[3], sh[3]), 0.f) * occv;
            if constexpr (FINAL) {
                float* o = (float*)outv;
                const int sp = yo * 128 + x;
                o[((size_t)(co0 + 0) * 2 + z0) * HW + sp] = v0;
                o[((size_t)(co0 + 1) * 2 + z0) * HW + sp] = v1;
                o[((size_t)(co0 + 2) * 2 + z0) * HW + sp] = v2;
                o[((size_t)(co0 + 3) * 2 + z0) * HW + sp] = v3;
            } else {
                _Float16* o = (_Float16*)outv;
                half4v hv;
                hv[0] = (_Float16)v0; hv[1] = (_Float16)v1;
                hv[2] = (_Float16)v2; hv[3] = (_Float16)v3;
                *(half4v*)(o + ((size_t)(z0 * 130 + (yo + 1)) * 130 + (x + 1)) * OCS + co0) = hv;
            }
        }
    }

    // ---- zero this block's share of the OUTPUT buffer's border cells ----
    if constexpr (!FINAL) {
        _Float16* o = (_Float16*)outv;
        constexpr int QC = OCS / 4;   // half4v quads per cell
        half4v zz;
        zz[0] = (_Float16)0.f; zz[1] = (_Float16)0.f; zz[2] = (_Float16)0.f; zz[3] = (_Float16)0.f;
        // x-border cells (x=0 and x=129) for this block's owned rows
        {
            const int slots = TR * 2 * QC;
            if (tid < slots) {
                int q = tid % QC;
                int c = tid / QC;
                int r = c >> 1;
                int side = (c & 1) ? 129 : 0;
                *(half4v*)(o + ((size_t)(z0 * 130 + (y0 + 1 + r)) * 130 + side) * OCS + q * 4) = zz;
            }
        }
        // y-edge rows (padded rows 0 and 129) at grid edges
        const int YPMAX = (TR == 2) ? 63 : 127;
        if (yp == 0) {
            for (int g = tid; g < 130 * QC; g += 512) {
                int cell = g / QC, q = g % QC;
                *(half4v*)(o + ((size_t)(z0 * 130 + 0) * 130 + cell) * OCS + q * 4) = zz;
            }
        }
        if (yp == YPMAX) {
            for (int g = tid; g < 130 * QC; g += 512) {
                int cell = g / QC, q = g % QC;
                *(half4v*)(o + ((size_t)(z0 * 130 + 129) * 130 + cell) * OCS + q * 4) = zz;
            }
        }
    }
}

extern "C" void kernel_launch(void* const* d_in, const int* in_sizes, int n_in,
                              void* d_out, int out_size, void* d_ws, size_t ws_size,
                              hipStream_t stream) {
    const float* vf    = (const float*)d_in[0];
    const int*   coors = (const int*)d_in[1];
    const float* w0    = (const float*)d_in[2];
    const float* w1    = (const float*)d_in[3];
    const float* w2    = (const float*)d_in[4];
    const float* w64   = (const float*)d_in[5];
    const float* w10   = (const float*)d_in[6];
    const float* g32   = (const float*)d_in[7];
    const float* b32   = (const float*)d_in[8];
    const float* m32   = (const float*)d_in[9];
    const float* v32   = (const float*)d_in[10];
    const float* g64   = (const float*)d_in[11];
    const float* b64   = (const float*)d_in[12];
    const float* m64   = (const float*)d_in[13];
    const float* v64   = (const float*)d_in[14];
    const int N = in_sizes[0] / 16;

    float* out_f = (float*)d_out;

    // ---- workspace layout (bytes): occ0 adjacent to R0 so ONE zero4 covers both ----
    const size_t R0       = 0;            // 21,632,000 (P32 A; front = D4A)
    const size_t OFF_OCC0 = 21632000;     // 262,144
    const size_t R1       = 21894144;     // 21,632,000 (P32 B / R2 D8; front = D4B)
    const size_t R3       = 43526144;     // 19,468,800 (P64 D8)
    const size_t OFF_OCC1 = 62994944;     // 131,072
    const size_t OFF_OCC2 = 63126016;     // 65,536
    const size_t OFF_OCC3 = 63191552;     // 32,768
    const size_t OFF_AP   = 63224320;     // 1,794,048
    const size_t TOTAL_BYTES = 65018368;

    if (ws_size < TOTAL_BYTES) {
        write_code_f32<<<dim3(1), dim3(64), 0, stream>>>(out_f, 1.0e8f);
        return;
    }

    char* wsb = (char*)d_ws;
    _Float16* A0p = (_Float16*)(wsb + R0);
    _Float16* A1p = (_Float16*)(wsb + R1);
    _Float16* A3p = (_Float16*)(wsb + R3);
    _Float16* A2p = A1p;
    unsigned char* occ0 = (unsigned char*)(wsb + OFF_OCC0);
    unsigned char* occ1 = (unsigned char*)(wsb + OFF_OCC1);
    unsigned char* occ2 = (unsigned char*)(wsb + OFF_OCC2);
    unsigned char* occ3 = (unsigned char*)(wsb + OFF_OCC3);
    _Float16* AP = (_Float16*)(wsb + OFF_AP);

    const size_t W_A0 = 0, W_A1 = 27648, W_A2 = 55296, W_A3 = 110592, W_A10 = 884736;

    // ---- prologue: ONE zero covering R0 (scatter target) + occ0 ----
    {
        const int n4 = (int)((OFF_OCC0 + 262144) / 16);
        zero4<<<dim3((n4 + 255) / 256), dim3(256), 0, stream>>>((float4*)wsb, n4);
    }

    // ---- fused weight pack ----
    {
        PackDesc pd;
        int units[11] = {3456, 3456, 6912, 13824, 13824, 13824, 13824, 13824, 13824, 13824, 1536};
        const float* srcs[11] = {w0, w1, w2,
                                 w64 + 0 * 110592, w64 + 1 * 110592, w64 + 2 * 110592,
                                 w64 + 3 * 110592, w64 + 4 * 110592, w64 + 5 * 110592,
                                 w64 + 6 * 110592, w10};
        int offs[11] = {(int)W_A0, (int)W_A1, (int)W_A2,
                        (int)(W_A3 + 0 * 110592), (int)(W_A3 + 1 * 110592), (int)(W_A3 + 2 * 110592),
                        (int)(W_A3 + 3 * 110592), (int)(W_A3 + 4 * 110592), (int)(W_A3 + 5 * 110592),
                        (int)(W_A3 + 6 * 110592), (int)W_A10};
        int cinr[11] = {16, 32, 32, 64, 64, 64, 64, 64, 64, 64, 64};
        int cinp[11] = {32, 32, 32, 64, 64, 64, 64, 64, 64, 64, 64};
        int cout[11] = {32, 32, 64, 64, 64, 64, 64, 64, 64, 64, 64};
        int khw[11]  = {3, 3, 3, 3, 3, 3, 3, 3, 3, 3, 1};
        int c = 0;
        for (int i = 0; i < 11; ++i) {
            pd.src[i] = srcs[i]; pd.dstoff[i] = offs[i]; pd.cum[i] = c; c += units[i];
            pd.cinr[i] = cinr[i]; pd.cinp[i] = cinp[i]; pd.cout[i] = cout[i]; pd.khw[i] = khw[i];
        }
        pd.cum[11] = c;
        pack_all<<<dim3((c + 255) / 256), dim3(256), 0, stream>>>(pd, AP);
    }

    scatter_f16<<<dim3((N + 255) / 256), dim3(256), 0, stream>>>(vf, coors, A0p, occ0, N);
    pool_occ<<<dim3(HW / 256), dim3(256), 0, stream>>>(occ0, occ1, occ2, occ3);

    // L0: 16(pad32)->32, D16  (R0 -> R1; epilogue zeroes R1 borders)
    conv_mfma<32, 32, 3, 3, 1, 16, 16, false><<<dim3(16 * 64), dim3(512), 0, stream>>>(
        A0p, AP + W_A0, g32, b32, m32, v32, occ0, A1p);
    // L1: 32->32, D16  (R1 -> R0; epilogue re-zeroes R0 borders)
    conv_mfma<32, 32, 3, 3, 1, 16, 16, false><<<dim3(16 * 64), dim3(512), 0, stream>>>(
        A1p, AP + W_A1, g32 + 32, b32 + 32, m32 + 32, v32 + 32, occ0, A0p);
    // L2: 32->64, stride-z 2, D16->8  (R0 -> R2; epilogue zeroes R2 borders in D8/CS72 geometry)
    conv_mfma<32, 64, 3, 3, 2, 16, 8, false><<<dim3(8 * 64), dim3(512), 0, stream>>>(
        A0p, AP + W_A2, g64, b64, m64, v64, occ1, A2p);
    // L3..L5: 64->64, D8  (R2 -> R3 -> R2 -> R3)
    conv_mfma<64, 64, 3, 3, 1, 8, 8, false><<<dim3(8 * 64), dim3(512), 0, stream>>>(
        A2p, AP + W_A3 + 0 * 110592, g64 + 64, b64 + 64, m64 + 64, v64 + 64, occ1, A3p);
    conv_mfma<64, 64, 3, 3, 1, 8, 8, false><<<dim3(8 * 64), dim3(512), 0, stream>>>(
        A3p, AP + W_A3 + 1 * 110592, g64 + 128, b64 + 128, m64 + 128, v64 + 128, occ1, A2p);
    conv_mfma<64, 64, 3, 3, 1, 8, 8, false><<<dim3(8 * 64), dim3(512), 0, stream>>>(
        A2p, AP + W_A3 + 2 * 110592, g64 + 192, b64 + 192, m64 + 192, v64 + 192, occ1, A3p);
    // L6: 64->64, stride-z 2, D8->4  (R3 -> D4A), TR=1: grid 512, 4 waves/SIMD
    conv_mfma<64, 64, 3, 3, 2, 8, 4, false, 1><<<dim3(4 * 128), dim3(512), 0, stream>>>(
        A3p, AP + W_A3 + 3 * 110592, g64 + 256, b64 + 256, m64 + 256, v64 + 256, occ2, A0p);
    // L7..L9: 64->64, D4  (D4A -> D4B -> D4A -> D4B), TR=1
    conv_mfma<64, 64, 3, 3, 1, 4, 4, false, 1><<<dim3(4 * 128), dim3(512), 0, stream>>>(
        A0p, AP + W_A3 + 4 * 110592, g64 + 320, b64 + 320, m64 + 320, v64 + 320, occ2, A1p);
    conv_mfma<64, 64, 3, 3, 1, 4, 4, false, 1><<<dim3(4 * 128), dim3(512), 0, stream>>>(
        A1p, AP + W_A3 + 5 * 110592, g64 + 384, b64 + 384, m64 + 384, v64 + 384, occ2, A0p);
    conv_mfma<64, 64, 3, 3, 1, 4, 4, false, 1><<<dim3(4 * 128), dim3(512), 0, stream>>>(
        A0p, AP + W_A3 + 6 * 110592, g64 + 448, b64 + 448, m64 + 448, v64 + 448, occ2, A1p);
    // L10: 64->64, kernel (3,1,1), stride-z 2, D4->2, f32 out -> d_out  (D4B -> out)
    conv_mfma<64, 64, 3, 1, 2, 4, 2, true><<<dim3(2 * 64), dim3(512), 0, stream>>>(
        A1p, AP + W_A10, g64 + 512, b64 + 512, m64 + 512, v64 + 512, occ3, out_f);
}

// Round 23
// 297.617 us; speedup vs baseline: 1.4864x; 1.0057x over previous
//
#include <hip/hip_runtime.h>

#define HW 16384   // 128*128

typedef _Float16 half8  __attribute__((ext_vector_type(8)));
typedef _Float16 half4v __attribute__((ext_vector_type(4)));
typedef float    f32x4  __attribute__((ext_vector_type(4)));

typedef __attribute__((address_space(3))) unsigned int lds_u32;
typedef const __attribute__((address_space(1))) unsigned int glb_u32;

// direct global->LDS 16B DMA (no VGPR round trip)
__device__ __forceinline__ void gl_lds16(const void* g, void* l) {
    __builtin_amdgcn_global_load_lds((glb_u32*)g, (lds_u32*)l, 16, 0, 0);
}

// ---------------- zero fill (float4 granularity) ----------------
__global__ void zero4(float4* __restrict__ p, int n4) {
    int i = blockIdx.x * 256 + threadIdx.x;
    if (i < n4) p[i] = make_float4(0.f, 0.f, 0.f, 0.f);
}

__global__ void write_code_f32(float* out, float v) {
    if (threadIdx.x == 0 && blockIdx.x == 0) out[0] = v;
}

// ---------------- fused weight pack: all 11 layers in one dispatch ----------------
struct PackDesc {
    const float* src[11];
    int dstoff[11];
    int cum[12];
    int cinr[11];
    int cinp[11];
    int cout[11];
    int khw[11];
};

__global__ void pack_all(PackDesc pd, _Float16* __restrict__ AP) {
    int u = blockIdx.x * 256 + threadIdx.x;
    if (u >= pd.cum[11]) return;
    int s = 0;
    while (u >= pd.cum[s + 1]) ++s;
    int idx = u - pd.cum[s];
    const int CINr = pd.cinr[s], CINp = pd.cinp[s], KHW = pd.khw[s];
    const int KD = 3;
    const int NSTEPS = KD * KHW * KHW * (CINp / 32);
    const float* W = pd.src[s];
    int lane = idx & 63;
    int st   = (idx >> 6) % NSTEPS;
    int grp  = idx / (NSTEPS * 64);
    int k0  = st * 32 + (lane >> 4) * 8;
    int t   = k0 / CINp;
    int ci0 = k0 % CINp;
    int co  = grp * 16 + (lane & 15);
    int khw2 = KHW * KHW;
    int dz = t / khw2, r = t % khw2, dy = r / KHW, dx = r % KHW;
    half8 hv;
    for (int j = 0; j < 8; ++j) {
        int ci = ci0 + j;
        float wv = (ci < CINr)
            ? W[(((size_t)co * CINr + ci) * KD + dz) * khw2 + dy * KHW + dx] : 0.0f;
        hv[j] = (_Float16)wv;
    }
    *(half8*)(AP + pd.dstoff[s] + ((size_t)(grp * NSTEPS + st) * 64 + lane) * 8) = hv;
}

// ---------------- scatter voxels into [z][130][130][40] f16 grid ----------------
__global__ void scatter_f16(const float* __restrict__ vf, const int* __restrict__ coors,
                            _Float16* __restrict__ act, unsigned char* __restrict__ occ, int n) {
    int i = blockIdx.x * 256 + threadIdx.x;
    if (i >= n) return;
    int z = coors[i * 4 + 1];
    int y = coors[i * 4 + 2];
    int x = coors[i * 4 + 3];
    size_t cell = ((size_t)(z * 130 + (y + 1)) * 130 + (x + 1)) * 40;
    for (int c = 0; c < 16; ++c) act[cell + c] = (_Float16)vf[i * 16 + c];
    occ[z * HW + y * 128 + x] = 1;
}

// ---------------- pool occupancy (u8) over z: D16 -> D8 -> D4 -> D2 ----------------
__global__ void pool_occ(const unsigned char* __restrict__ o0, unsigned char* __restrict__ o1,
                         unsigned char* __restrict__ o2, unsigned char* __restrict__ o3) {
    int p = blockIdx.x * 256 + threadIdx.x;
    if (p >= HW) return;
    unsigned char a[16];
    for (int z = 0; z < 16; ++z) a[z] = o0[z * HW + p];
    for (int z = 0; z < 8; ++z) { a[z] = a[2 * z] | a[2 * z + 1]; o1[z * HW + p] = a[z]; }
    for (int z = 0; z < 4; ++z) { a[z] = a[2 * z] | a[2 * z + 1]; o2[z * HW + p] = a[z]; }
    for (int z = 0; z < 2; ++z) { a[z] = a[2 * z] | a[2 * z + 1]; o3[z * HW + p] = a[z]; }
}

// ---------------- MFMA implicit-GEMM conv + BN + ReLU + occ, LDS-staged ----------------
// act : [DIN][130][130][CS=CINp+8] f16 (y/x padded by 1; border real-channels zero).
// Staging: global_load_lds 16B granules (guarded tail), LDS == linear stripe image.
// out : intermediate [DOUT][130][130][COUT+8] f16 ; FINAL [COUT*2][128][128] f32.
// Non-FINAL epilogue also ZEROES its output buffer's border cells (writer-covers-
// -output invariant) so no separate border_zero dispatches are needed.
// TR=2: block 512thr = 8 waves (ylocal, x-half, co-half), 2 rows x 128 px, 4-row stripe.
// TR=1: block 512thr = 8 waves (x-half, co-group),        1 row  x 128 px, 3-row stripe.
template <int CINp, int COUT, int KD, int KHW, int SZ, int DIN, int DOUT, bool FINAL, int TR = 2>
__global__ __launch_bounds__(512, 4)
void conv_mfma(const _Float16* __restrict__ act, const _Float16* __restrict__ apack,
               const float* __restrict__ gm, const float* __restrict__ bt,
               const float* __restrict__ mn, const float* __restrict__ vr,
               const unsigned char* __restrict__ occ, void* __restrict__ outv) {
    constexpr int PADXY  = KHW / 2;
    constexpr int CB     = CINp / 32;
    constexpr int MGT    = COUT / 16;                 // total co-groups
    constexpr int MGW    = (TR == 2) ? ((MGT + 1) / 2) : 1;   // co-groups per wave
    static_assert(TR == 2 || MGT == 4, "TR=1 requires COUT=64");
    constexpr int NSTEPS = KD * KHW * KHW * CB;
    constexpr int CS     = CINp + 8;
    constexpr int OCS    = COUT + 8;
    constexpr int SROWS  = TR + 2;                    // staged rows
    constexpr int NGRAN  = SROWS * 130 * CS / 8;
    constexpr int NIT    = (NGRAN + 511) / 512;
    constexpr int OFS    = 1 - PADXY;
    constexpr int NWG    = DOUT * (128 / TR);

    __shared__ _Float16 smem[SROWS * 130 * CS];

    const int bid0 = blockIdx.x;
    const int bid = (bid0 & 7) * (NWG / 8) + (bid0 >> 3);   // XCD-chunked swizzle
    const int yp = (TR == 2) ? (bid & 63) : (bid & 127);
    const int z0 = (TR == 2) ? (bid >> 6) : (bid >> 7);
    const int y0 = yp * TR;
    const int tid  = threadIdx.x;
    const int w    = tid >> 6;
    const int lane = tid & 63;
    const int ylocal = (TR == 2) ? (w >> 2) : 0;
    const int x0w    = (TR == 2) ? (((w >> 1) & 1) * 64) : ((w & 1) * 64);
    const int chsel  = (TR == 2) ? ((MGT > 1) ? (w & 1) : 0) : (w >> 1);
    const int n  = lane & 15;
    const int kg = lane >> 4;

    f32x4 acc[MGW][4];
    #pragma unroll
    for (int m = 0; m < MGW; ++m)
        #pragma unroll
        for (int t = 0; t < 4; ++t) { acc[m][t][0] = 0.f; acc[m][t][1] = 0.f; acc[m][t][2] = 0.f; acc[m][t][3] = 0.f; }

    const int zb = z0 * SZ;
    const int dzlo = (zb == 0) ? 1 : 0;
    const int dzhi = (zb + KD - 1 > DIN) ? (KD - 1) : KD;

    for (int dz = dzlo; dz < dzhi; ++dz) {
        const int zi = zb + dz - 1;
        __syncthreads();   // previous iteration's LDS reads complete
        // ---- stage SROWS-row stripe via global_load_lds ----
        const _Float16* src = act + (size_t)(zi * 130 + y0) * (130 * CS);
        #pragma unroll
        for (int it = 0; it < NIT; ++it) {
            int g = it * 512 + tid;
            if (g < NGRAN) gl_lds16(src + (size_t)g * 8, smem + (size_t)g * 8);
        }
        asm volatile("s_waitcnt vmcnt(0)" ::: "memory");
        __syncthreads();
        // ---- K-loop over taps (straight-line) ----
        #pragma unroll
        for (int dy = 0; dy < KHW; ++dy) {
            #pragma unroll
            for (int dx = 0; dx < KHW; ++dx) {
                #pragma unroll
                for (int cb = 0; cb < CB; ++cb) {
                    const int sabs = dz * (KHW * KHW * CB) + (dy * KHW + dx) * CB + cb;
                    half8 a[MGW];
                    #pragma unroll
                    for (int mg = 0; mg < MGW; ++mg)
                        a[mg] = *(const half8*)(apack
                            + ((size_t)((chsel * MGW + mg) * NSTEPS + sabs) * 64 + lane) * 8);
                    const _Float16* bp = smem
                        + ((ylocal + dy + OFS) * 130 + x0w + n + dx + OFS) * CS + cb * 32 + kg * 8;
                    #pragma unroll
                    for (int nt = 0; nt < 4; ++nt) {
                        half8 b = *(const half8*)(bp + nt * 16 * CS);
                        #pragma unroll
                        for (int mg = 0; mg < MGW; ++mg)
                            acc[mg][nt] = __builtin_amdgcn_mfma_f32_16x16x32_f16(a[mg], b, acc[mg][nt], 0, 0, 0);
                    }
                }
            }
        }
    }

    // ---- epilogue: BN + ReLU + occ, store ----
    const int yo = y0 + ylocal;
    #pragma unroll
    for (int mg = 0; mg < MGW; ++mg) {
        const int co0 = (chsel * MGW + mg) * 16 + kg * 4;
        const f32x4 gv = *(const f32x4*)(gm + co0);
        const f32x4 bv = *(const f32x4*)(bt + co0);
        const f32x4 mv = *(const f32x4*)(mn + co0);
        const f32x4 vv = *(const f32x4*)(vr + co0);
        float sc[4], sh[4];
        #pragma unroll
        for (int r = 0; r < 4; ++r) {
            sc[r] = gv[r] * __frsqrt_rn(vv[r] + 1e-5f);
            sh[r] = bv[r] - mv[r] * sc[r];
        }
        #pragma unroll
        for (int nt = 0; nt < 4; ++nt) {
            const int x = x0w + nt * 16 + n;
            const float occv = (float)occ[z0 * HW + yo * 128 + x];
            float v0 = fmaxf(fmaf(acc[mg][nt][0], sc[0], sh[0]), 0.f) * occv;
            float v1 = fmaxf(fmaf(acc[mg][nt][1], sc[1], sh[1]), 0.f) * occv;
            float v2 = fmaxf(fmaf(acc[mg][nt][2], sc[2], sh[2]), 0.f) * occv;
            float v3 = fmaxf(fmaf(acc[mg][nt][3], sc[3], sh[3]), 0.f) * occv;
            if constexpr (FINAL) {
                float* o = (float*)outv;
                const int sp = yo * 128 + x;
                o[((size_t)(co0 + 0) * 2 + z0) * HW + sp] = v0;
                o[((size_t)(co0 + 1) * 2 + z0) * HW + sp] = v1;
                o[((size_t)(co0 + 2) * 2 + z0) * HW + sp] = v2;
                o[((size_t)(co0 + 3) * 2 + z0) * HW + sp] = v3;
            } else {
                _Float16* o = (_Float16*)outv;
                half4v hv;
                hv[0] = (_Float16)v0; hv[1] = (_Float16)v1;
                hv[2] = (_Float16)v2; hv[3] = (_Float16)v3;
                *(half4v*)(o + ((size_t)(z0 * 130 + (yo + 1)) * 130 + (x + 1)) * OCS + co0) = hv;
            }
        }
    }

    // ---- zero this block's share of the OUTPUT buffer's border cells ----
    if constexpr (!FINAL) {
        _Float16* o = (_Float16*)outv;
        constexpr int QC = OCS / 4;   // half4v quads per cell
        half4v zz;
        zz[0] = (_Float16)0.f; zz[1] = (_Float16)0.f; zz[2] = (_Float16)0.f; zz[3] = (_Float16)0.f;
        // x-border cells (x=0 and x=129) for this block's owned rows
        {
            const int slots = TR * 2 * QC;
            if (tid < slots) {
                int q = tid % QC;
                int c = tid / QC;
                int r = c >> 1;
                int side = (c & 1) ? 129 : 0;
                *(half4v*)(o + ((size_t)(z0 * 130 + (y0 + 1 + r)) * 130 + side) * OCS + q * 4) = zz;
            }
        }
        // y-edge rows (padded rows 0 and 129) at grid edges
        const int YPMAX = (TR == 2) ? 63 : 127;
        if (yp == 0) {
            for (int g = tid; g < 130 * QC; g += 512) {
                int cell = g / QC, q = g % QC;
                *(half4v*)(o + ((size_t)(z0 * 130 + 0) * 130 + cell) * OCS + q * 4) = zz;
            }
        }
        if (yp == YPMAX) {
            for (int g = tid; g < 130 * QC; g += 512) {
                int cell = g / QC, q = g % QC;
                *(half4v*)(o + ((size_t)(z0 * 130 + 129) * 130 + cell) * OCS + q * 4) = zz;
            }
        }
    }
}

extern "C" void kernel_launch(void* const* d_in, const int* in_sizes, int n_in,
                              void* d_out, int out_size, void* d_ws, size_t ws_size,
                              hipStream_t stream) {
    const float* vf    = (const float*)d_in[0];
    const int*   coors = (const int*)d_in[1];
    const float* w0    = (const float*)d_in[2];
    const float* w1    = (const float*)d_in[3];
    const float* w2    = (const float*)d_in[4];
    const float* w64   = (const float*)d_in[5];
    const float* w10   = (const float*)d_in[6];
    const float* g32   = (const float*)d_in[7];
    const float* b32   = (const float*)d_in[8];
    const float* m32   = (const float*)d_in[9];
    const float* v32   = (const float*)d_in[10];
    const float* g64   = (const float*)d_in[11];
    const float* b64   = (const float*)d_in[12];
    const float* m64   = (const float*)d_in[13];
    const float* v64   = (const float*)d_in[14];
    const int N = in_sizes[0] / 16;

    float* out_f = (float*)d_out;

    // ---- workspace layout (bytes): occ0 adjacent to R0 so ONE zero4 covers both ----
    const size_t R0       = 0;            // 21,632,000 (P32 A; front = D4A)
    const size_t OFF_OCC0 = 21632000;     // 262,144
    const size_t R1       = 21894144;     // 21,632,000 (P32 B / R2 D8; front = D4B)
    const size_t R3       = 43526144;     // 19,468,800 (P64 D8)
    const size_t OFF_OCC1 = 62994944;     // 131,072
    const size_t OFF_OCC2 = 63126016;     // 65,536
    const size_t OFF_OCC3 = 63191552;     // 32,768
    const size_t OFF_AP   = 63224320;     // 1,794,048
    const size_t TOTAL_BYTES = 65018368;

    if (ws_size < TOTAL_BYTES) {
        write_code_f32<<<dim3(1), dim3(64), 0, stream>>>(out_f, 1.0e8f);
        return;
    }

    char* wsb = (char*)d_ws;
    _Float16* A0p = (_Float16*)(wsb + R0);
    _Float16* A1p = (_Float16*)(wsb + R1);
    _Float16* A3p = (_Float16*)(wsb + R3);
    _Float16* A2p = A1p;
    unsigned char* occ0 = (unsigned char*)(wsb + OFF_OCC0);
    unsigned char* occ1 = (unsigned char*)(wsb + OFF_OCC1);
    unsigned char* occ2 = (unsigned char*)(wsb + OFF_OCC2);
    unsigned char* occ3 = (unsigned char*)(wsb + OFF_OCC3);
    _Float16* AP = (_Float16*)(wsb + OFF_AP);

    const size_t W_A0 = 0, W_A1 = 27648, W_A2 = 55296, W_A3 = 110592, W_A10 = 884736;

    // ---- prologue: ONE zero covering R0 (scatter target) + occ0 ----
    {
        const int n4 = (int)((OFF_OCC0 + 262144) / 16);
        zero4<<<dim3((n4 + 255) / 256), dim3(256), 0, stream>>>((float4*)wsb, n4);
    }

    // ---- fused weight pack ----
    {
        PackDesc pd;
        int units[11] = {3456, 3456, 6912, 13824, 13824, 13824, 13824, 13824, 13824, 13824, 1536};
        const float* srcs[11] = {w0, w1, w2,
                                 w64 + 0 * 110592, w64 + 1 * 110592, w64 + 2 * 110592,
                                 w64 + 3 * 110592, w64 + 4 * 110592, w64 + 5 * 110592,
                                 w64 + 6 * 110592, w10};
        int offs[11] = {(int)W_A0, (int)W_A1, (int)W_A2,
                        (int)(W_A3 + 0 * 110592), (int)(W_A3 + 1 * 110592), (int)(W_A3 + 2 * 110592),
                        (int)(W_A3 + 3 * 110592), (int)(W_A3 + 4 * 110592), (int)(W_A3 + 5 * 110592),
                        (int)(W_A3 + 6 * 110592), (int)W_A10};
        int cinr[11] = {16, 32, 32, 64, 64, 64, 64, 64, 64, 64, 64};
        int cinp[11] = {32, 32, 32, 64, 64, 64, 64, 64, 64, 64, 64};
        int cout[11] = {32, 32, 64, 64, 64, 64, 64, 64, 64, 64, 64};
        int khw[11]  = {3, 3, 3, 3, 3, 3, 3, 3, 3, 3, 1};
        int c = 0;
        for (int i = 0; i < 11; ++i) {
            pd.src[i] = srcs[i]; pd.dstoff[i] = offs[i]; pd.cum[i] = c; c += units[i];
            pd.cinr[i] = cinr[i]; pd.cinp[i] = cinp[i]; pd.cout[i] = cout[i]; pd.khw[i] = khw[i];
        }
        pd.cum[11] = c;
        pack_all<<<dim3((c + 255) / 256), dim3(256), 0, stream>>>(pd, AP);
    }

    scatter_f16<<<dim3((N + 255) / 256), dim3(256), 0, stream>>>(vf, coors, A0p, occ0, N);
    pool_occ<<<dim3(HW / 256), dim3(256), 0, stream>>>(occ0, occ1, occ2, occ3);

    // L0: 16(pad32)->32, D16  (R0 -> R1; epilogue zeroes R1 borders)
    conv_mfma<32, 32, 3, 3, 1, 16, 16, false><<<dim3(16 * 64), dim3(512), 0, stream>>>(
        A0p, AP + W_A0, g32, b32, m32, v32, occ0, A1p);
    // L1: 32->32, D16  (R1 -> R0; epilogue re-zeroes R0 borders)
    conv_mfma<32, 32, 3, 3, 1, 16, 16, false><<<dim3(16 * 64), dim3(512), 0, stream>>>(
        A1p, AP + W_A1, g32 + 32, b32 + 32, m32 + 32, v32 + 32, occ0, A0p);
    // L2: 32->64, stride-z 2, D16->8  (R0 -> R2; epilogue zeroes R2 borders in D8/CS72 geometry)
    conv_mfma<32, 64, 3, 3, 2, 16, 8, false><<<dim3(8 * 64), dim3(512), 0, stream>>>(
        A0p, AP + W_A2, g64, b64, m64, v64, occ1, A2p);
    // L3..L5: 64->64, D8  (R2 -> R3 -> R2 -> R3)
    conv_mfma<64, 64, 3, 3, 1, 8, 8, false><<<dim3(8 * 64), dim3(512), 0, stream>>>(
        A2p, AP + W_A3 + 0 * 110592, g64 + 64, b64 + 64, m64 + 64, v64 + 64, occ1, A3p);
    conv_mfma<64, 64, 3, 3, 1, 8, 8, false><<<dim3(8 * 64), dim3(512), 0, stream>>>(
        A3p, AP + W_A3 + 1 * 110592, g64 + 128, b64 + 128, m64 + 128, v64 + 128, occ1, A2p);
    conv_mfma<64, 64, 3, 3, 1, 8, 8, false><<<dim3(8 * 64), dim3(512), 0, stream>>>(
        A2p, AP + W_A3 + 2 * 110592, g64 + 192, b64 + 192, m64 + 192, v64 + 192, occ1, A3p);
    // L6: 64->64, stride-z 2, D8->4  (R3 -> D4A), TR=1: grid 512, 4 waves/SIMD
    conv_mfma<64, 64, 3, 3, 2, 8, 4, false, 1><<<dim3(4 * 128), dim3(512), 0, stream>>>(
        A3p, AP + W_A3 + 3 * 110592, g64 + 256, b64 + 256, m64 + 256, v64 + 256, occ2, A0p);
    // L7..L9: 64->64, D4  (D4A -> D4B -> D4A -> D4B), TR=1
    conv_mfma<64, 64, 3, 3, 1, 4, 4, false, 1><<<dim3(4 * 128), dim3(512), 0, stream>>>(
        A0p, AP + W_A3 + 4 * 110592, g64 + 320, b64 + 320, m64 + 320, v64 + 320, occ2, A1p);
    conv_mfma<64, 64, 3, 3, 1, 4, 4, false, 1><<<dim3(4 * 128), dim3(512), 0, stream>>>(
        A1p, AP + W_A3 + 5 * 110592, g64 + 384, b64 + 384, m64 + 384, v64 + 384, occ2, A0p);
    conv_mfma<64, 64, 3, 3, 1, 4, 4, false, 1><<<dim3(4 * 128), dim3(512), 0, stream>>>(
        A0p, AP + W_A3 + 6 * 110592, g64 + 448, b64 + 448, m64 + 448, v64 + 448, occ2, A1p);
    // L10: 64->64, kernel (3,1,1), stride-z 2, D4->2, f32 out -> d_out  (D4B -> out), TR=1
    conv_mfma<64, 64, 3, 1, 2, 4, 2, true, 1><<<dim3(2 * 128), dim3(512), 0, stream>>>(
        A1p, AP + W_A10, g64 + 512, b64 + 512, m64 + 512, v64 + 512, occ3, out_f);
}